// Round 6
// baseline (237.656 us; speedup 1.0000x reference)
//
#include <hip/hip_runtime.h>
#include <hip/hip_bf16.h>
#include <stdint.h>

#define BB 2
#define NN 2048
#define CC 1024
#define HH 16
#define DD 64
#define C3 3072

typedef __attribute__((ext_vector_type(8))) short bf16x8;
typedef __attribute__((ext_vector_type(4))) float f32x4;
typedef __attribute__((ext_vector_type(4))) unsigned short ushort4_t;

__device__ __forceinline__ unsigned short f2bf(float f) {
  union { float f; unsigned u; } v; v.f = f;
  unsigned r = v.u + 0x7FFFu + ((v.u >> 16) & 1u);
  return (unsigned short)(r >> 16);
}

#if __has_builtin(__builtin_amdgcn_exp2f)
#define EXP2(x) __builtin_amdgcn_exp2f(x)
#else
#define EXP2(x) exp2f(x)
#endif

// 0.125 (1/sqrt(D)) * log2(e): folded into Q so softmax is raw v_exp_f32 (2^x)
#define QSCALE 0.18033688f

// async global->LDS, 16B per lane; LDS dest must be wave-uniform base + lane*16
#define GLDS(g, l) __builtin_amdgcn_global_load_lds( \
    (const __attribute__((address_space(1))) void*)(g), \
    (__attribute__((address_space(3))) void*)(l), 16, 0, 0)

// ----------------------------------------- merged fp32->bf16 converts (3 bufs)
__global__ __launch_bounds__(256) void k_cvt(
    const float* __restrict__ x, const float* __restrict__ wq,
    const float* __restrict__ wp,
    unsigned short* __restrict__ xb, unsigned short* __restrict__ wqb,
    unsigned short* __restrict__ wpb)
{
  int blk = blockIdx.x;
  const float* s; unsigned short* d; int i;
  if (blk < 4096)      { s = x;  d = xb;  i = blk * 256 + threadIdx.x; }
  else if (blk < 7168) { s = wq; d = wqb; i = (blk - 4096) * 256 + threadIdx.x; }
  else                 { s = wp; d = wpb; i = (blk - 7168) * 256 + threadIdx.x; }
  float4 v = ((const float4*)s)[i];
  ushort4_t o;
  o.x = f2bf(v.x); o.y = f2bf(v.y); o.z = f2bf(v.z); o.w = f2bf(v.w);
  ((ushort4_t*)d)[i] = o;
}

// -------------------------------- GEMM1 fused: qkv = x@Wqkv^T + b, RoPE, pack
// BK=64, XOR-swizzled LDS (16B chunk ^= row&7): conflict-free frag reads,
// 16 K-iterations (half the barriers of BK=32).
__global__ __launch_bounds__(256) void k_gemm_qkv(
    const unsigned short* __restrict__ A, const unsigned short* __restrict__ Bt,
    const float* __restrict__ bias,
    const float* __restrict__ cosb, const float* __restrict__ sinb,
    unsigned short* __restrict__ Qg, unsigned short* __restrict__ Kg,
    unsigned short* __restrict__ Vnd)
{
  __shared__ __align__(16) unsigned short As[128 * 64];
  __shared__ __align__(16) unsigned short Bs[128 * 64];
  const int tid  = threadIdx.x;
  const int lane = tid & 63;
  const int wave = tid >> 6;
  const int bm = blockIdx.y * 128;
  const int bn = blockIdx.x * 128;
  const int wm = (wave >> 1) * 64;
  const int wn = (wave & 1) * 64;
  const int frow   = lane & 15;
  const int fchunk = lane >> 4;
  const int K = 1024;

  f32x4 acc[4][4] = {};

  const int srow[4] = { tid >> 3, 32 + (tid >> 3), 64 + (tid >> 3), 96 + (tid >> 3) };
  int scol[4];
#pragma unroll
  for (int j = 0; j < 4; ++j) scol[j] = ((tid & 7) ^ (srow[j] & 7)) * 8;

  for (int k0 = 0; k0 < K; k0 += 64) {
#pragma unroll
    for (int j = 0; j < 4; ++j) {
      GLDS(A  + (size_t)(bm + srow[j]) * K + k0 + scol[j], As + (size_t)(j * 256 + tid) * 8);
      GLDS(Bt + (size_t)(bn + srow[j]) * K + k0 + scol[j], Bs + (size_t)(j * 256 + tid) * 8);
    }
    __syncthreads();

#pragma unroll
    for (int kh = 0; kh < 2; ++kh) {
      bf16x8 af[4], bfr[4];
#pragma unroll
      for (int t = 0; t < 4; ++t) {
        int ra = wm + t * 16 + frow;
        int rb = wn + t * 16 + frow;
        af[t]  = *(const bf16x8*)(As + ra * 64 + (((kh * 4 + fchunk) ^ (ra & 7)) << 3));
        bfr[t] = *(const bf16x8*)(Bs + rb * 64 + (((kh * 4 + fchunk) ^ (rb & 7)) << 3));
      }
#pragma unroll
      for (int mt = 0; mt < 4; ++mt)
#pragma unroll
        for (int nt = 0; nt < 4; ++nt)
          acc[mt][nt] = __builtin_amdgcn_mfma_f32_16x16x32_bf16(af[mt], bfr[nt], acc[mt][nt], 0, 0, 0);
    }
    __syncthreads();
  }

  const int er0  = (lane >> 4) * 4;
  const int ecol = lane & 15;
  const int region = bn >> 10;                    // wave-uniform
  unsigned short* dstQK = (region == 0) ? Qg : Kg;

#pragma unroll
  for (int nt = 0; nt < 4; ++nt) {
    const int col = bn + wn + nt * 16 + ecol;     // global col in [0,3072)
    const float bv = bias[col];
    const int c64 = (wn + nt * 16 + ecol) & 63;   // d within head
    const int h   = (col >> 6) & 15;
    const int ii  = c64 >> 1;
#pragma unroll
    for (int mt = 0; mt < 4; ++mt)
#pragma unroll
      for (int r = 0; r < 4; ++r) {
        const int rowg = bm + wm + mt * 16 + er0 + r;
        const int b = rowg >> 11, n = rowg & (NN - 1);
        float v = acc[mt][nt][r] + bv;
        float vp = __shfl_xor(v, 1, 64);          // pair partner (col^1)
        const size_t o = ((size_t)(b * HH + h) * NN + n) * DD + c64;
        if (region == 2) {
          Vnd[o] = f2bf(v);
        } else {
          float cth = cosb[n * 32 + ii], sth = sinb[n * 32 + ii];
          float ov = (c64 & 1) ? (vp * sth + v * cth)
                               : (v * cth - vp * sth);
          if (region == 0) ov *= QSCALE;
          dstQK[o] = f2bf(ov);
        }
      }
  }
}

// ------------------------------------- V transpose: Vnd[bh][n][d] -> Vt[bh][d][n]
__global__ __launch_bounds__(256) void k_vt(
    const unsigned short* __restrict__ Vnd, unsigned short* __restrict__ Vt)
{
  __shared__ unsigned short t[64][66];
  const int tid = threadIdx.x;
  const int bh = blockIdx.x >> 5;
  const int n0 = (blockIdx.x & 31) * 64;

  const unsigned short* src = Vnd + ((size_t)bh * NN + n0) * DD;
  const int nl = tid >> 2, d0 = (tid & 3) * 16;
#pragma unroll
  for (int j = 0; j < 4; ++j) {
    ushort4_t v = *(const ushort4_t*)(src + (size_t)nl * DD + d0 + j * 4);
    t[nl][d0 + j * 4 + 0] = v.x;
    t[nl][d0 + j * 4 + 1] = v.y;
    t[nl][d0 + j * 4 + 2] = v.z;
    t[nl][d0 + j * 4 + 3] = v.w;
  }
  __syncthreads();
  const int d = tid >> 2, m0 = (tid & 3) * 16;
  unsigned short* dst = Vt + ((size_t)bh * DD + d) * NN + n0 + m0;
#pragma unroll
  for (int j = 0; j < 4; ++j) {
    ushort4_t o;
    o.x = t[m0 + j * 4 + 0][d];
    o.y = t[m0 + j * 4 + 1][d];
    o.z = t[m0 + j * 4 + 2][d];
    o.w = t[m0 + j * 4 + 3][d];
    *(ushort4_t*)(dst + j * 4) = o;
  }
}

// ----------------------------------------------------- flash attention v6
// kv-SPLIT: grid 1024 = bh(32) x qtile(16) x half(2); each block does half the
// kv axis (16 iters) and writes UNNORMALIZED O (f32) + l partials; combine
// kernel finishes exactly (max-free softmax => partials sum exactly).
// 32 q/wave (DS-read floor), LDS 40KB -> 4 blocks/CU = 16 waves/CU.
// Ps halved to per-kh chunks (wave-serial DS ordering makes reuse safe).
__global__ __launch_bounds__(256) void k_attn(
    const unsigned short* __restrict__ Qg, const unsigned short* __restrict__ Kg,
    const unsigned short* __restrict__ Vtg,
    float* __restrict__ Op, float* __restrict__ lp)
{
  __shared__ __align__(16) unsigned short Ks[2][64 * 64];  // [kv][d] swizzled
  __shared__ __align__(16) unsigned short Vs[2][64 * 64];  // [d][kv] swizzled
  __shared__ __align__(16) unsigned short Ps[4][32 * 32];  // per-wave [m][kv32]

  const int tid  = threadIdx.x;
  const int lane = tid & 63;
  const int wave = tid >> 6;
  const int blk  = blockIdx.x;
  const int bh   = blk >> 5;
  const int qt   = (blk >> 1) & 15;
  const int half = blk & 1;
  const int q0 = qt * 128 + wave * 32;
  const int frow   = lane & 15;
  const int fchunk = lane >> 4;
  const int er0  = (lane >> 4) * 4;
  const int ecol = lane & 15;

  const unsigned short* Qb = Qg  + (size_t)bh * NN * DD;
  const unsigned short* Kb = Kg  + (size_t)bh * NN * DD;
  const unsigned short* Vb = Vtg + (size_t)bh * DD * NN;
  const int jbase = half * (NN / 2);

  bf16x8 qf[2][2];
#pragma unroll
  for (int m = 0; m < 2; ++m)
#pragma unroll
    for (int kt = 0; kt < 2; ++kt)
      qf[m][kt] = *(const bf16x8*)(Qb + (size_t)(q0 + m * 16 + frow) * DD + kt * 32 + fchunk * 8);

  bf16x8 ones;
#pragma unroll
  for (int i = 0; i < 8; ++i) ones[i] = (short)0x3F80;

  f32x4 oacc[2][4] = {};
  f32x4 lacc[2] = {};

  const int row0 = tid >> 3, cc0 = tid & 7;
  const int sw0 = (cc0 ^ (row0 & 7)) * 8;

  GLDS(Kb + (size_t)(jbase + row0) * DD + sw0,      Ks[0] + (size_t)tid * 8);
  GLDS(Vb + (size_t)row0 * NN + jbase + sw0,        Vs[0] + (size_t)tid * 8);
  GLDS(Kb + (size_t)(jbase + row0 + 32) * DD + sw0, Ks[0] + (size_t)(tid + 256) * 8);
  GLDS(Vb + (size_t)(row0 + 32) * NN + jbase + sw0, Vs[0] + (size_t)(tid + 256) * 8);

  for (int t = 0; t < NN / 128; ++t) {
    const int p = t & 1;
    __syncthreads();

    if (t + 1 < NN / 128) {
      const int j = jbase + (t + 1) * 64;
      GLDS(Kb + (size_t)(j + row0) * DD + sw0,      Ks[1 - p] + (size_t)tid * 8);
      GLDS(Vb + (size_t)row0 * NN + j + sw0,        Vs[1 - p] + (size_t)tid * 8);
      GLDS(Kb + (size_t)(j + row0 + 32) * DD + sw0, Ks[1 - p] + (size_t)(tid + 256) * 8);
      GLDS(Vb + (size_t)(row0 + 32) * NN + j + sw0, Vs[1 - p] + (size_t)(tid + 256) * 8);
    }

    // S = Q K^T : 2 m-frags x 4 kv-frags
    f32x4 sacc[2][4] = {};
#pragma unroll
    for (int nt = 0; nt < 4; ++nt) {
      int kr = nt * 16 + frow;
      bf16x8 kf0 = *(const bf16x8*)(Ks[p] + kr * 64 + ((fchunk       ^ (kr & 7)) << 3));
      bf16x8 kf1 = *(const bf16x8*)(Ks[p] + kr * 64 + (((fchunk + 4) ^ (kr & 7)) << 3));
#pragma unroll
      for (int m = 0; m < 2; ++m) {
        sacc[m][nt] = __builtin_amdgcn_mfma_f32_16x16x32_bf16(qf[m][0], kf0, sacc[m][nt], 0, 0, 0);
        sacc[m][nt] = __builtin_amdgcn_mfma_f32_16x16x32_bf16(qf[m][1], kf1, sacc[m][nt], 0, 0, 0);
      }
    }

    // per-kh half: exp -> Ps (32x32 per wave) -> l-MFMA + PV
#pragma unroll
    for (int kh = 0; kh < 2; ++kh) {
#pragma unroll
      for (int m = 0; m < 2; ++m)
#pragma unroll
        for (int r = 0; r < 4; ++r) {
          int prow = m * 16 + er0 + r;
#pragma unroll
          for (int nh = 0; nh < 2; ++nh) {
            float pv = EXP2(sacc[m][kh * 2 + nh][r]);
            union { float f; unsigned u; } cv; cv.f = pv;
            int cl = nh * 16 + ecol;
            Ps[wave][prow * 32 + (((cl >> 3) ^ (prow & 3)) << 3) + (cl & 7)] =
                (unsigned short)(cv.u >> 16);
          }
        }

      bf16x8 pf[2];
#pragma unroll
      for (int m = 0; m < 2; ++m) {
        int pr = m * 16 + frow;
        pf[m] = *(const bf16x8*)(&Ps[wave][pr * 32 + ((fchunk ^ (pr & 3)) << 3)]);
        lacc[m] = __builtin_amdgcn_mfma_f32_16x16x32_bf16(pf[m], ones, lacc[m], 0, 0, 0);
      }
#pragma unroll
      for (int dt = 0; dt < 4; ++dt) {
        int vr = dt * 16 + frow;
        bf16x8 vf = *(const bf16x8*)(Vs[p] + vr * 64 + (((kh * 4 + fchunk) ^ (vr & 7)) << 3));
#pragma unroll
        for (int m = 0; m < 2; ++m)
          oacc[m][dt] = __builtin_amdgcn_mfma_f32_16x16x32_bf16(pf[m], vf, oacc[m][dt], 0, 0, 0);
      }
    }
  }

  // write f32 partials (unnormalized) + l
  float* Oh = Op + (size_t)half * (32u * NN * DD);
#pragma unroll
  for (int m = 0; m < 2; ++m) {
#pragma unroll
    for (int dt = 0; dt < 4; ++dt)
#pragma unroll
      for (int r = 0; r < 4; ++r) {
        int qrow = q0 + m * 16 + er0 + r;
        int d = dt * 16 + ecol;
        Oh[((size_t)bh * NN + qrow) * DD + d] = oacc[m][dt][r];
      }
    if (ecol == 0) {
#pragma unroll
      for (int r = 0; r < 4; ++r) {
        int qrow = q0 + m * 16 + er0 + r;
        lp[(size_t)half * (32 * NN) + bh * NN + qrow] = lacc[m][r];
      }
    }
  }
}

// ------------------- combine halves: aob = (Oa+Ob)/(la+lb), bf16 [b][n][c]
__global__ __launch_bounds__(256) void k_combine(
    const float* __restrict__ Op, const float* __restrict__ lp,
    unsigned short* __restrict__ aob)
{
  int idx = blockIdx.x * 256 + threadIdx.x;     // 1,048,576 = 65536 q x 16 d4
  int q  = idx >> 4;                            // bh*2048 + n
  int d4 = (idx & 15) * 4;
  const float4 a = *(const float4*)(Op + (size_t)q * DD + d4);
  const float4 b = *(const float4*)(Op + (size_t)(32u * NN * DD) + (size_t)q * DD + d4);
  float inv = 1.0f / (lp[q] + lp[32 * NN + q]);
  int bh = q >> 11, n = q & (NN - 1);
  int bb = bh >> 4, h = bh & 15;
  ushort4_t o;
  o.x = f2bf((a.x + b.x) * inv);
  o.y = f2bf((a.y + b.y) * inv);
  o.z = f2bf((a.z + b.z) * inv);
  o.w = f2bf((a.w + b.w) * inv);
  *(ushort4_t*)(aob + ((size_t)(bb * NN + n) * CC) + h * DD + d4) = o;
}

// ------------------------------- GEMM2: out = aob @ Wproj^T + b (fp32 out)
// BK=64 + swizzle; 64x128 tiles, grid (8,64).
__global__ __launch_bounds__(256) void k_gemm_proj(
    const unsigned short* __restrict__ A, const unsigned short* __restrict__ Bt,
    const float* __restrict__ bias, float* __restrict__ Co)
{
  __shared__ __align__(16) unsigned short As[64 * 64];
  __shared__ __align__(16) unsigned short Bs[128 * 64];
  const int tid  = threadIdx.x;
  const int lane = tid & 63;
  const int wave = tid >> 6;
  const int bm = blockIdx.y * 64;
  const int bn = blockIdx.x * 128;
  const int wm = (wave >> 1) * 32;
  const int wn = (wave & 1) * 64;
  const int frow   = lane & 15;
  const int fchunk = lane >> 4;
  const int K = 1024;

  f32x4 acc[2][4] = {};

  const int r0 = tid >> 3;
  const int sc0 = ((tid & 7) ^ (r0 & 7)) * 8;
  const int r1 = 32 + r0;
  const int sc1 = ((tid & 7) ^ (r1 & 7)) * 8;

  for (int k0 = 0; k0 < K; k0 += 64) {
    GLDS(A + (size_t)(bm + r0) * K + k0 + sc0, As + (size_t)tid * 8);
    GLDS(A + (size_t)(bm + r1) * K + k0 + sc1, As + (size_t)(tid + 256) * 8);
#pragma unroll
    for (int j = 0; j < 4; ++j) {
      int rb = j * 32 + r0;
      int scb = ((tid & 7) ^ (rb & 7)) * 8;
      GLDS(Bt + (size_t)(bn + rb) * K + k0 + scb, Bs + (size_t)(j * 256 + tid) * 8);
    }
    __syncthreads();

#pragma unroll
    for (int kh = 0; kh < 2; ++kh) {
      bf16x8 af[2], bfr[4];
#pragma unroll
      for (int t = 0; t < 2; ++t) {
        int ra = wm + t * 16 + frow;
        af[t] = *(const bf16x8*)(As + ra * 64 + (((kh * 4 + fchunk) ^ (ra & 7)) << 3));
      }
#pragma unroll
      for (int t = 0; t < 4; ++t) {
        int rb = wn + t * 16 + frow;
        bfr[t] = *(const bf16x8*)(Bs + rb * 64 + (((kh * 4 + fchunk) ^ (rb & 7)) << 3));
      }
#pragma unroll
      for (int mt = 0; mt < 2; ++mt)
#pragma unroll
        for (int nt = 0; nt < 4; ++nt)
          acc[mt][nt] = __builtin_amdgcn_mfma_f32_16x16x32_bf16(af[mt], bfr[nt], acc[mt][nt], 0, 0, 0);
    }
    __syncthreads();
  }

  const int er0  = (lane >> 4) * 4;
  const int ecol = lane & 15;
#pragma unroll
  for (int nt = 0; nt < 4; ++nt) {
    int col = bn + wn + nt * 16 + ecol;
    float bv = bias[col];
#pragma unroll
    for (int mt = 0; mt < 2; ++mt)
#pragma unroll
      for (int r = 0; r < 4; ++r) {
        int rowg = bm + wm + mt * 16 + er0 + r;
        Co[(size_t)rowg * CC + col] = acc[mt][nt][r] + bv;
      }
  }
}

// ---------------------------------------------------------------- launcher
extern "C" void kernel_launch(void* const* d_in, const int* in_sizes, int n_in,
                              void* d_out, int out_size, void* d_ws, size_t ws_size,
                              hipStream_t stream)
{
  const float* x      = (const float*)d_in[0];
  const float* w_qkv  = (const float*)d_in[1];
  const float* b_qkv  = (const float*)d_in[2];
  const float* w_proj = (const float*)d_in[3];
  const float* b_proj = (const float*)d_in[4];
  const float* fcos   = (const float*)d_in[5];
  const float* fsin   = (const float*)d_in[6];
  float* out = (float*)d_out;

  char* ws = (char*)d_ws;
  unsigned short* xb     = (unsigned short*)(ws);              //  8 MB
  unsigned short* wqkvb  = (unsigned short*)(ws + 8388608);    //  6 MB
  unsigned short* wprojb = (unsigned short*)(ws + 14680064);   //  2 MB
  unsigned short* Qb     = (unsigned short*)(ws + 16777216);   //  8 MB
  unsigned short* Kb     = (unsigned short*)(ws + 25165824);   //  8 MB
  unsigned short* Vnd    = (unsigned short*)(ws + 33554432);   //  8 MB
  unsigned short* Vtb    = (unsigned short*)(ws + 41943040);   //  8 MB
  unsigned short* aob    = (unsigned short*)(ws + 50331648);   //  8 MB
  float*          Op     = (float*)(ws + 58720256);            // 32 MB
  float*          lp     = (float*)(ws + 92274688);            // 0.5 MB

  k_cvt<<<8192, 256, 0, stream>>>(x, w_qkv, w_proj, xb, wqkvb, wprojb);

  k_gemm_qkv<<<dim3(24, 32), 256, 0, stream>>>(xb, wqkvb, b_qkv, fcos, fsin,
                                               Qb, Kb, Vnd);
  k_vt<<<1024, 256, 0, stream>>>(Vnd, Vtb);

  k_attn<<<1024, 256, 0, stream>>>(Qb, Kb, Vtb, Op, lp);
  k_combine<<<4096, 256, 0, stream>>>(Op, lp, aob);

  k_gemm_proj<<<dim3(8, 64), 256, 0, stream>>>(aob, wprojb, b_proj, out);
}